// Round 2
// baseline (1865.688 us; speedup 1.0000x reference)
//
#include <hip/hip_runtime.h>
#include <math.h>

#define NB 8
#define NC 3
#define NN 4096
#define NK 40
#define NF 64

// ---------------- cross-lane helpers (wave64) ----------------
__device__ __forceinline__ unsigned long long sx64(unsigned long long v, int m) {
  int lo = __shfl_xor((int)(unsigned)v, m, 64);
  int hi = __shfl_xor((int)(v >> 32), m, 64);
  return ((unsigned long long)(unsigned)hi << 32) | (unsigned)lo;
}
__device__ __forceinline__ unsigned long long bc64(unsigned long long v, int src) {
  int lo = __shfl((int)(unsigned)v, src, 64);
  int hi = __shfl((int)(v >> 32), src, 64);
  return ((unsigned long long)(unsigned)hi << 32) | (unsigned)lo;
}

// bitonic compare-exchange; vl = virtual index of this element
__device__ __forceinline__ void ce64(unsigned long long &x, unsigned vl, unsigned k, unsigned j) {
  unsigned long long o = sx64(x, (int)j);
  bool takeMax = (((vl & j) == 0u) == ((vl & k) == 0u)); // final order: descending
  bool gt = x > o;
  x = (takeMax == gt) ? x : o;
}

// full descending sort of 128 elements held as 2 regs/lane (a: vlane=lane, b: vlane=lane+64)
__device__ __forceinline__ void sort128(unsigned long long &a, unsigned long long &b, int lane) {
  const unsigned va = (unsigned)lane, vb = (unsigned)lane + 64u;
  #pragma unroll
  for (unsigned k = 2; k <= 64; k <<= 1) {
    #pragma unroll
    for (unsigned j = k >> 1; j >= 1; j >>= 1) {
      ce64(a, va, k, j);
      ce64(b, vb, k, j);
    }
  }
  // k = 128, j = 64: partner is the other register, same lane; descending -> a takes max
  {
    unsigned long long mx = a > b ? a : b;
    unsigned long long mn = a > b ? b : a;
    a = mx; b = mn;
  }
  #pragma unroll
  for (unsigned j = 32; j >= 1; j >>= 1) {
    ce64(a, va, 128u, j);
    ce64(b, vb, 128u, j);
  }
}

// ---------------- k0: build xyzs = (x,y,z,|p|^2) ----------------
__global__ __launch_bounds__(256) void k0_prep(const float* __restrict__ x, float4* __restrict__ xyzs) {
  const int i = blockIdx.x * 256 + threadIdx.x;   // 0..32767
  const int b = i >> 12, n = i & 4095;
  const float* xb = x + b * (NC * NN);
  const float a0 = xb[n], a1 = xb[n + NN], a2 = xb[n + 2 * NN];
  const float sq = fmaf(a2, a2, fmaf(a1, a1, a0 * a0));
  xyzs[i] = make_float4(a0, a1, a2, sq);
}

// ---------------- k1: exact KNN top-40 (wave per query), f64 distances ----------------
__global__ __launch_bounds__(256) void k1_knn(const float4* __restrict__ xyzs, int* __restrict__ idxo) {
  __shared__ float4 xl[NN];                    // 64 KB
  __shared__ unsigned long long kbuf[4][128];  // 4 KB
  const int tid = threadIdx.x;
  const int b = blockIdx.x >> 6;
  const int blkq = blockIdx.x & 63;
  const int w = tid >> 6, lane = tid & 63;
  const float4* xb = xyzs + b * NN;
  for (int i = tid; i < NN; i += 256) xl[i] = xb[i];
  __syncthreads();
  unsigned long long* bufw = kbuf[w];
  const unsigned long long lmask = (1ull << lane) - 1ull;

  for (int qi = 0; qi < 16; ++qi) {
    const int q = blkq * 64 + w * 16 + qi;
    const float4 Q = xl[q];
    const double Qx = (double)Q.x, Qy = (double)Q.y, Qz = (double)Q.z;
    const double Qw = fma(Qz, Qz, fma(Qy, Qy, Qx * Qx));
    unsigned long long a = 0ull;     // sorted top-64, descending by lane
    unsigned long long thr = 0ull;   // current 40th-best key (conservative)
    int cnt = 0;
    for (int m0 = 0; m0 < NN; m0 += 64) {
      const int m = m0 + lane;
      const float4 P = xl[m];
      const double Px = (double)P.x, Py = (double)P.y, Pz = (double)P.z;
      const double Pw = fma(Pz, Pz, fma(Py, Py, Px * Px));
      const double dot = fma(Qz, Pz, fma(Qy, Py, Qx * Px));
      const double pdd = 2.0 * dot - Qw - Pw;          // = -(dist^2), larger = closer
      const float pd = (float)pdd;                     // single rounding from exact
      unsigned u = __float_as_uint(pd);
      u ^= (unsigned)((int)u >> 31) | 0x80000000u;     // order-preserving float->uint
      const unsigned long long key = ((unsigned long long)u << 32) | (unsigned)(4095 - m);
      const bool cand = key > thr;
      const unsigned long long bal = __ballot(cand);
      if (bal) {
        const int rank = __popcll(bal & lmask);
        if (cand) bufw[cnt + rank] = key;
        cnt += __popcll(bal);
        if (cnt >= 64) {                                // merge buffer into sorted list
          int off = 0;
          while (off < cnt) {
            unsigned long long bb = (off + lane < cnt) ? bufw[off + lane] : 0ull;
            sort128(a, bb, lane);
            off += 64;
          }
          cnt = 0;
          thr = bc64(a, 39);
        }
      }
    }
    {
      int off = 0;
      while (off < cnt) {
        unsigned long long bb = (off + lane < cnt) ? bufw[off + lane] : 0ull;
        sort128(a, bb, lane);
        off += 64;
      }
      cnt = 0;
    }
    if (lane < NK) idxo[(b * NN + q) * NK + lane] = 4095 - (int)(a & 0xFFFFFFFFull);
  }
}

// ---------------- k2: edge-feature moments (6 sums + 21 upper-tri products) ----------------
__global__ __launch_bounds__(256) void k2_mom(const float4* __restrict__ xyzs, const int* __restrict__ idx,
                                              float* __restrict__ part) {
  const int tid = threadIdx.x;
  const int gid = blockIdx.x * 256 + tid;
  float acc[27];
  #pragma unroll
  for (int j = 0; j < 27; ++j) acc[j] = 0.f;
  for (int i = 0; i < 10; ++i) {
    const int s = gid + i * 131072;          // B*N*K = 1310720 = 131072*10
    const int b = s / 163840;                // N*K
    const int r = s - b * 163840;
    const int n = r / 40;
    const int m = idx[s];
    const float4 ct = xyzs[b * NN + n];
    const float4 nb = xyzs[b * NN + m];
    const float e[6] = {nb.x - ct.x, nb.y - ct.y, nb.z - ct.z, ct.x, ct.y, ct.z};
    int t = 6;
    #pragma unroll
    for (int c = 0; c < 6; ++c) {
      acc[c] += e[c];
      #pragma unroll
      for (int d = c; d < 6; ++d) { acc[t] = fmaf(e[c], e[d], acc[t]); ++t; }
    }
  }
  const int w = tid >> 6, lane = tid & 63;
  __shared__ float red[4][27];
  #pragma unroll
  for (int j = 0; j < 27; ++j) {
    float v = acc[j];
    #pragma unroll
    for (int mm = 1; mm < 64; mm <<= 1) v += __shfl_xor(v, mm, 64);
    if (lane == 0) red[w][j] = v;
  }
  __syncthreads();
  if (tid < 27) part[blockIdx.x * 27 + tid] = red[0][tid] + red[1][tid] + red[2][tid] + red[3][tid];
}

// ---------------- k3: BN1 stats (analytic from moments), fold into W1 ----------------
__global__ void k3_stats1(const float* __restrict__ part, const float* __restrict__ W1,
                          const float* __restrict__ g1, const float* __restrict__ b1,
                          float* __restrict__ s1) {
  __shared__ float S[27];
  const int t = threadIdx.x;
  if (t < 27) {
    double s = 0.0;
    for (int p = 0; p < 512; ++p) s += (double)part[p * 27 + t];
    S[t] = (float)s;
  }
  __syncthreads();
  if (t < 64) {
    const float inv = 1.f / 1310720.f;
    float mu[6];
    #pragma unroll
    for (int c = 0; c < 6; ++c) mu[c] = S[c] * inv;
    float M[6][6];
    int tt = 6;
    #pragma unroll
    for (int c = 0; c < 6; ++c) {
      #pragma unroll
      for (int d = c; d < 6; ++d) { const float v = S[tt] * inv; M[c][d] = v; M[d][c] = v; ++tt; }
    }
    float wv[6];
    #pragma unroll
    for (int c = 0; c < 6; ++c) wv[c] = W1[t * 6 + c];
    float mean = 0.f;
    #pragma unroll
    for (int c = 0; c < 6; ++c) mean = fmaf(wv[c], mu[c], mean);
    float e2 = 0.f;
    #pragma unroll
    for (int c = 0; c < 6; ++c) {
      float rowdot = 0.f;
      #pragma unroll
      for (int d = 0; d < 6; ++d) rowdot = fmaf(wv[d], M[c][d], rowdot);
      e2 = fmaf(wv[c], rowdot, e2);
    }
    const float var = e2 - mean * mean;
    const float aa = g1[t] / sqrtf(var + 1e-5f);
    const float cc = b1[t] - mean * aa;
    #pragma unroll
    for (int c = 0; c < 6; ++c) s1[t * 8 + c] = aa * wv[c];  // pre-folded W1' = a1*W1
    s1[t * 8 + 6] = cc;
    s1[t * 8 + 7] = 0.f;
  }
}

// ---------------- k4: per-feature sum / sumsq of y2 (for BN2 stats) ----------------
__global__ __launch_bounds__(256, 2) void k4_stats2(const float4* __restrict__ xyzs, const int* __restrict__ idx,
                                                    const float* __restrict__ s1, const float* __restrict__ W2,
                                                    float* __restrict__ part) {
  const int b = blockIdx.x >> 7;
  const int nblk = blockIdx.x & 127;
  const int tid = threadIdx.x, w = tid >> 6, lane = tid & 63;
  const int n = nblk * 32 + w * 8 + (lane >> 3);
  const int kb = lane & 7;
  const float4 ct = xyzs[b * NN + n];
  const int* ib = idx + (b * NN + n) * NK;
  float acc_s[64], acc_q[64];
  #pragma unroll
  for (int f = 0; f < 64; ++f) { acc_s[f] = 0.f; acc_q[f] = 0.f; }
  for (int kc = 0; kc < 5; ++kc) {
    const int m = ib[kc * 8 + kb];
    const float4 nb = xyzs[b * NN + m];
    const float e0 = nb.x - ct.x, e1 = nb.y - ct.y, e2v = nb.z - ct.z;
    float z1[64];
    #pragma unroll
    for (int g = 0; g < 64; ++g) {
      const float* r = s1 + g * 8;
      float z = r[6];
      z = fmaf(r[0], e0, z);
      z = fmaf(r[1], e1, z);
      z = fmaf(r[2], e2v, z);
      z = fmaf(r[3], ct.x, z);
      z = fmaf(r[4], ct.y, z);
      z = fmaf(r[5], ct.z, z);
      z1[g] = z >= 0.f ? z : 0.2f * z;
    }
    #pragma unroll
    for (int f = 0; f < 64; ++f) {
      const float* wr = W2 + f * 64;
      float p0 = 0.f, p1 = 0.f, p2 = 0.f, p3 = 0.f;
      #pragma unroll
      for (int g = 0; g < 64; g += 4) {
        p0 = fmaf(wr[g + 0], z1[g + 0], p0);
        p1 = fmaf(wr[g + 1], z1[g + 1], p1);
        p2 = fmaf(wr[g + 2], z1[g + 2], p2);
        p3 = fmaf(wr[g + 3], z1[g + 3], p3);
      }
      const float y2 = (p0 + p1) + (p2 + p3);
      acc_s[f] += y2;
      acc_q[f] = fmaf(y2, y2, acc_q[f]);
    }
  }
  __shared__ float red[4][128];
  #pragma unroll
  for (int f = 0; f < 64; ++f) {
    float v = acc_s[f];
    #pragma unroll
    for (int mm = 1; mm < 64; mm <<= 1) v += __shfl_xor(v, mm, 64);
    float qv = acc_q[f];
    #pragma unroll
    for (int mm = 1; mm < 64; mm <<= 1) qv += __shfl_xor(qv, mm, 64);
    if (lane == 0) { red[w][f] = v; red[w][64 + f] = qv; }
  }
  __syncthreads();
  if (tid < 128) part[blockIdx.x * 128 + tid] = red[0][tid] + red[1][tid] + red[2][tid] + red[3][tid];
}

// ---------------- k5: reduce BN2 partials -> affine (a2, c2) ----------------
__global__ void k5_stats2b(const float* __restrict__ part, const float* __restrict__ g2,
                           const float* __restrict__ b2, float* __restrict__ s2) {
  const int t = threadIdx.x;  // 128 threads
  double s = 0.0;
  for (int p = 0; p < 1024; ++p) s += (double)part[p * 128 + t];
  __shared__ float S[128];
  S[t] = (float)s;
  __syncthreads();
  if (t < 64) {
    const float inv = 1.f / 1310720.f;
    const float mean = S[t] * inv;
    const float var = S[t + 64] * inv - mean * mean;
    const float aa = g2[t] / sqrtf(var + 1e-5f);
    const float cc = b2[t] - mean * aa;
    s2[2 * t] = aa;
    s2[2 * t + 1] = cc;
  }
}

// ---------------- k6: final pass, y2 -> bn2 -> lrelu -> max over k ----------------
__global__ __launch_bounds__(256, 2) void k6_final(const float4* __restrict__ xyzs, const int* __restrict__ idx,
                                                   const float* __restrict__ s1, const float* __restrict__ W2,
                                                   const float* __restrict__ s2, float* __restrict__ out) {
  const int b = blockIdx.x >> 7;
  const int nblk = blockIdx.x & 127;
  const int tid = threadIdx.x, w = tid >> 6, lane = tid & 63;
  const int n = nblk * 32 + w * 8 + (lane >> 3);
  const int kb = lane & 7;
  const float4 ct = xyzs[b * NN + n];
  const int* ib = idx + (b * NN + n) * NK;
  float mx[64];
  #pragma unroll
  for (int f = 0; f < 64; ++f) mx[f] = -3.0e38f;
  for (int kc = 0; kc < 5; ++kc) {
    const int m = ib[kc * 8 + kb];
    const float4 nb = xyzs[b * NN + m];
    const float e0 = nb.x - ct.x, e1 = nb.y - ct.y, e2v = nb.z - ct.z;
    float z1[64];
    #pragma unroll
    for (int g = 0; g < 64; ++g) {
      const float* r = s1 + g * 8;
      float z = r[6];
      z = fmaf(r[0], e0, z);
      z = fmaf(r[1], e1, z);
      z = fmaf(r[2], e2v, z);
      z = fmaf(r[3], ct.x, z);
      z = fmaf(r[4], ct.y, z);
      z = fmaf(r[5], ct.z, z);
      z1[g] = z >= 0.f ? z : 0.2f * z;
    }
    #pragma unroll
    for (int f = 0; f < 64; ++f) {
      const float* wr = W2 + f * 64;
      float p0 = 0.f, p1 = 0.f, p2 = 0.f, p3 = 0.f;
      #pragma unroll
      for (int g = 0; g < 64; g += 4) {
        p0 = fmaf(wr[g + 0], z1[g + 0], p0);
        p1 = fmaf(wr[g + 1], z1[g + 1], p1);
        p2 = fmaf(wr[g + 2], z1[g + 2], p2);
        p3 = fmaf(wr[g + 3], z1[g + 3], p3);
      }
      const float y2 = (p0 + p1) + (p2 + p3);
      float tv = fmaf(y2, s2[2 * f], s2[2 * f + 1]);
      tv = tv >= 0.f ? tv : 0.2f * tv;
      mx[f] = fmaxf(mx[f], tv);
    }
  }
  #pragma unroll
  for (int f = 0; f < 64; ++f) {
    float m = mx[f];
    m = fmaxf(m, __shfl_xor(m, 1, 64));
    m = fmaxf(m, __shfl_xor(m, 2, 64));
    m = fmaxf(m, __shfl_xor(m, 4, 64));
    if (kb == 0) out[(b * NF + f) * NN + n] = m;
  }
}

extern "C" void kernel_launch(void* const* d_in, const int* in_sizes, int n_in,
                              void* d_out, int out_size, void* d_ws, size_t ws_size,
                              hipStream_t stream) {
  const float* x  = (const float*)d_in[0];
  const float* W1 = (const float*)d_in[1];
  const float* g1 = (const float*)d_in[2];
  const float* b1 = (const float*)d_in[3];
  const float* W2 = (const float*)d_in[4];
  const float* g2 = (const float*)d_in[5];
  const float* b2 = (const float*)d_in[6];
  float* out = (float*)d_out;
  char* ws = (char*)d_ws;
  // workspace layout (16B-aligned slabs), total ~6.35 MB
  float4* xyzs = (float4*)ws;                                              // 524288 B
  int*    idx  = (int*)(ws + 524288);                                      // 5242880 B
  float*  part2 = (float*)(ws + 524288 + 5242880);                         // 55296 B
  float*  s1    = (float*)(ws + 524288 + 5242880 + 55296);                 // 2048 B
  float*  part4 = (float*)(ws + 524288 + 5242880 + 55296 + 2048);          // 524288 B
  float*  s2    = (float*)(ws + 524288 + 5242880 + 55296 + 2048 + 524288); // 512 B

  k0_prep<<<128, 256, 0, stream>>>(x, xyzs);
  k1_knn<<<512, 256, 0, stream>>>(xyzs, idx);
  k2_mom<<<512, 256, 0, stream>>>(xyzs, idx, part2);
  k3_stats1<<<1, 64, 0, stream>>>(part2, W1, g1, b1, s1);
  k4_stats2<<<1024, 256, 0, stream>>>(xyzs, idx, s1, W2, part4);
  k5_stats2b<<<1, 128, 0, stream>>>(part4, g2, b2, s2);
  k6_final<<<1024, 256, 0, stream>>>(xyzs, idx, s1, W2, s2, out);
}